// Round 8
// baseline (777.563 us; speedup 1.0000x reference)
//
#include <hip/hip_runtime.h>
#include <hip/hip_bf16.h>

// Problem constants (fixed by setup_inputs)
#define T_STEPS 512
#define BATCH   256
#define NN      128                 // n
#define NEMB    1024                // N
#define M_ROWS  (T_STEPS * BATCH)   // 131072
#define NOISE_K 0.13416407864998738f  // sqrt(2/alpha * sigma^2)
#define NB      16                  // batches per block (one wave)
#define CH      4                   // steps per staged noise chunk
#define NSTEP   (T_STEPS - 1)       // 511 update steps
#define NCH     ((NSTEP + CH - 1) / CH)  // 128 chunks (last runs 3 steps)

typedef short s16x8 __attribute__((ext_vector_type(8)));
typedef float f32x4 __attribute__((ext_vector_type(4)));
typedef int   s32x2 __attribute__((ext_vector_type(2)));
typedef int   s32x4 __attribute__((ext_vector_type(4)));

union FragU { s32x4 i4; s16x8 s8; };

__device__ __forceinline__ unsigned short f2bf(float f) {
  union { float f; unsigned u; } v; v.f = f;
  unsigned r = v.u + 0x7fffu + ((v.u >> 16) & 1u);  // RNE
  return (unsigned short)(r >> 16);
}
__device__ __forceinline__ float bf2f(unsigned short s) {
  union { unsigned u; float f; } v; v.u = ((unsigned)s) << 16;
  return v.f;
}
// pack two f32 -> one u32 of 2 bf16 (low = first arg), RNE
__device__ __forceinline__ unsigned pkbf(float lo, float hi) {
  __hip_bfloat162 h = __float22bfloat162_rn(float2{lo, hi});
  union { __hip_bfloat162 h; unsigned u; } c; c.h = h; return c.u;
}

// ---------------------------------------------------------------------------
// Kernel 1: leaky-RNN recurrence on the MATRIX pipe. One wave (64 thr) per
// block, 16 batches/block, 16 blocks. Scalar formulations are pinned at
// ~1300+ cyc/step (r1: LDS-pipe 64 wave-b128/step; r7: VALU 256 instr/step);
// MFMA does the 16x128 @ 128x128 matvec in 40 mfma_16x16x32 (~200 cyc).
//   A-operand: W_rec rows as bf16 frags, resident in VGPRs (8 mf x 5 kc; the
//   5th K-block is W_inp padded 6->32, fusing the input projection).
//   B-operand: x (bf16) from a wave-private LDS buffer [f/4][b][4] (+8B/row
//   pad) -> D->B transpose is 8 ds_write_b64 + 8 ds_read_b64, conflict-free,
//   NO barriers (single wave, in-order DS pipe). x carry stays fp32 in regs.
//   rec_noise staged per-CH-step chunks via global_load_lds with swizzled
//   SOURCE addresses (f ^ (b&7)<<2) -> conflict-free LDS reads; counted
//   s_waitcnt vmcnt(32) so states-stores are never drained.
// states (bf16) written to ws in (T, B, n) layout; row m = t*B + b.
// ---------------------------------------------------------------------------
__global__ __launch_bounds__(64, 1) void rnn_mfma_kernel(
    const float* __restrict__ u,          // (6, T, B)
    const float* __restrict__ rec_noise,  // (B, T, n)
    const float* __restrict__ inp_noise,  // (B, T, 6)
    const float* __restrict__ W_inp,      // (n, 6)
    const float* __restrict__ W_rec,      // (n, n)
    unsigned short* __restrict__ states)  // (T, B, n) bf16
{
  const int b0 = blockIdx.x * NB;
  const int l  = threadIdx.x;   // 0..63
  const int lr = l & 15;        // batch (B/D cols) | row within A tile
  const int lg = l >> 4;        // k-chunk quarter  | D row group

  __shared__ char           xld[32 * 136];       // [f4][16b][4] bf16, 136B rows
  __shared__ float          rns[2][NB * CH * 128];  // [b][ts][f^swz], 64 KB
  __shared__ unsigned short uinl[NB * CH * 8];      // [b][ts][8] bf16

  // ---- W fragments (A-operand), bf16, resident
  s16x8 wA[8][5];
  #pragma unroll
  for (int mf = 0; mf < 8; ++mf) {
    const float* wrow = W_rec + (size_t)(mf * 16 + lr) * NN;
    #pragma unroll
    for (int kc = 0; kc < 4; ++kc) {
      f32x4 v0 = *(const f32x4*)(wrow + kc * 32 + lg * 8);
      f32x4 v1 = *(const f32x4*)(wrow + kc * 32 + lg * 8 + 4);
      FragU f;
      f.i4 = s32x4{(int)pkbf(v0.x, v0.y), (int)pkbf(v0.z, v0.w),
                   (int)pkbf(v1.x, v1.y), (int)pkbf(v1.z, v1.w)};
      wA[mf][kc] = f.s8;
    }
    float wi[8] = {0.f, 0.f, 0.f, 0.f, 0.f, 0.f, 0.f, 0.f};
    if (lg == 0) {
      #pragma unroll
      for (int j = 0; j < 6; ++j) wi[j] = W_inp[(mf * 16 + lr) * 6 + j];
    }
    FragU f;
    f.i4 = s32x4{(int)pkbf(wi[0], wi[1]), (int)pkbf(wi[2], wi[3]),
                 (int)pkbf(wi[4], wi[5]), (int)pkbf(wi[6], wi[7])};
    wA[mf][4] = f.s8;
  }

  // zero x_lds (x_0 = 0) and states row t=0 for this block's batches
  #pragma unroll
  for (int i = 0; i < 17; ++i) ((int*)xld)[l + 64 * i] = 0;
  #pragma unroll
  for (int i = 0; i < 4; ++i)
    *(s32x4*)((char*)states + (size_t)b0 * 256 + (l + 64 * i) * 16) =
        s32x4{0, 0, 0, 0};

  // per-lane source-offset pattern for swizzle-on-load (s = b&7)
  int loff[8];
  #pragma unroll
  for (int s = 0; s < 8; ++s)
    loff[s] = (l >> 5) * 512 + (((l & 31) * 16) ^ (s << 4));

  // ---- prologue: stage chunk 0
  #pragma unroll
  for (int b = 0; b < NB; ++b) {
    const char* gb = (const char*)rec_noise +
                     ((size_t)(b0 + b) * T_STEPS + 0) * 512 + loff[b & 7];
    float* db = &rns[0][b * 512];
    __builtin_amdgcn_global_load_lds(
        (const __attribute__((address_space(1))) void*)gb,
        (__attribute__((address_space(3))) void*)db, 16, 0, 0);
    __builtin_amdgcn_global_load_lds(
        (const __attribute__((address_space(1))) void*)(gb + 1024),
        (__attribute__((address_space(3))) void*)(db + 256), 16, 0, 0);
  }
  float uu[6], ii[6];
  {
    const int tb = lg;  // lane -> (b = lr, ts = lg)
    #pragma unroll
    for (int j = 0; j < 6; ++j) {
      uu[j] = u[(size_t)j * (T_STEPS * BATCH) + (size_t)tb * BATCH + b0 + lr];
      ii[j] = inp_noise[((size_t)(b0 + lr) * T_STEPS + tb) * 6 + j];
    }
  }
  asm volatile("s_waitcnt vmcnt(0)" ::: "memory");
  {
    s32x2 w01{(int)pkbf(uu[0] + NOISE_K * ii[0], uu[1] + NOISE_K * ii[1]),
              (int)pkbf(uu[2] + NOISE_K * ii[2], uu[3] + NOISE_K * ii[3])};
    s32x2 w23{(int)pkbf(uu[4] + NOISE_K * ii[4], uu[5] + NOISE_K * ii[5]), 0};
    *(s32x2*)&uinl[(lr * 4 + lg) * 8]     = w01;
    *(s32x2*)&uinl[(lr * 4 + lg) * 8 + 4] = w23;
  }

  float xo[8][4];
  #pragma unroll
  for (int mf = 0; mf < 8; ++mf)
    #pragma unroll
    for (int r = 0; r < 4; ++r) xo[mf][r] = 0.f;

  for (int c = 0; c < NCH; ++c) {
    const int cb = c & 1;
    if (c > 0) {
      // chunk-c loads (rec: 32, uin: 12) are older than the 32 stores of the
      // previous chunk's steps -> vmcnt(32) drains exactly the loads.
      asm volatile("s_waitcnt vmcnt(32)" ::: "memory");
      s32x2 w01{(int)pkbf(uu[0] + NOISE_K * ii[0], uu[1] + NOISE_K * ii[1]),
                (int)pkbf(uu[2] + NOISE_K * ii[2], uu[3] + NOISE_K * ii[3])};
      s32x2 w23{(int)pkbf(uu[4] + NOISE_K * ii[4], uu[5] + NOISE_K * ii[5]), 0};
      *(s32x2*)&uinl[(lr * 4 + lg) * 8]     = w01;
      *(s32x2*)&uinl[(lr * 4 + lg) * 8 + 4] = w23;
    }
    if (c + 1 < NCH) {
      const int t0 = (c + 1) * CH;
      #pragma unroll
      for (int b = 0; b < NB; ++b) {
        const char* gb = (const char*)rec_noise +
                         ((size_t)(b0 + b) * T_STEPS + t0) * 512 + loff[b & 7];
        float* db = &rns[cb ^ 1][b * 512];
        __builtin_amdgcn_global_load_lds(
            (const __attribute__((address_space(1))) void*)gb,
            (__attribute__((address_space(3))) void*)db, 16, 0, 0);
        __builtin_amdgcn_global_load_lds(
            (const __attribute__((address_space(1))) void*)(gb + 1024),
            (__attribute__((address_space(3))) void*)(db + 256), 16, 0, 0);
      }
      const int tb = t0 + lg;  // t0+lg <= 511: always in-bounds
      #pragma unroll
      for (int j = 0; j < 6; ++j) {
        uu[j] = u[(size_t)j * (T_STEPS * BATCH) + (size_t)tb * BATCH + b0 + lr];
        ii[j] = inp_noise[((size_t)(b0 + lr) * T_STEPS + tb) * 6 + j];
      }
    }

    #pragma unroll
    for (int ts = 0; ts < CH; ++ts) {
      const int t = c * CH + ts;
      if (t >= NSTEP) break;  // uniform: only trims last chunk

      // B fragments: previous x (bf16) from wave-private LDS
      s16x8 xb[4];
      #pragma unroll
      for (int kc = 0; kc < 4; ++kc) {
        const char* p = xld + (kc * 8 + lg * 2) * 136 + lr * 8;
        s32x2 r1 = *(const s32x2*)p;
        s32x2 r2 = *(const s32x2*)(p + 136);
        FragU f; f.i4 = s32x4{r1.x, r1.y, r2.x, r2.y};
        xb[kc] = f.s8;
      }
      FragU uf; uf.i4 = *(const s32x4*)&uinl[(lr * 4 + ts) * 8];
      const s16x8 ub = (lg == 0) ? uf.s8 : s16x8{0, 0, 0, 0, 0, 0, 0, 0};

      unsigned short* srow =
          states + ((size_t)(t + 1) * BATCH + b0 + lr) * NN + lg * 4;

      #pragma unroll
      for (int mf = 0; mf < 8; ++mf) {
        f32x4 a = f32x4{0.f, 0.f, 0.f, 0.f};
        a = __builtin_amdgcn_mfma_f32_16x16x32_bf16(wA[mf][0], xb[0], a, 0, 0, 0);
        a = __builtin_amdgcn_mfma_f32_16x16x32_bf16(wA[mf][1], xb[1], a, 0, 0, 0);
        a = __builtin_amdgcn_mfma_f32_16x16x32_bf16(wA[mf][2], xb[2], a, 0, 0, 0);
        a = __builtin_amdgcn_mfma_f32_16x16x32_bf16(wA[mf][3], xb[3], a, 0, 0, 0);
        a = __builtin_amdgcn_mfma_f32_16x16x32_bf16(wA[mf][4], ub,    a, 0, 0, 0);
        const f32x4 rn4 = *(const f32x4*)&rns[cb][lr * 512 + ts * 128 +
                               ((mf * 16 + lg * 4) ^ ((lr & 7) << 2))];
        float xn[4];
        #pragma unroll
        for (int r = 0; r < 4; ++r) {
          const float rl = fmaxf(a[r], 0.f);
          xn[r] = 0.9f * xo[mf][r] + 0.1f * (rl + NOISE_K * rn4[r]);
          xo[mf][r] = xn[r];
        }
        const s32x2 pw{(int)pkbf(xn[0], xn[1]), (int)pkbf(xn[2], xn[3])};
        *(s32x2*)(xld + (mf * 4 + lg) * 136 + lr * 8) = pw;  // publish for t+1
        *(s32x2*)(srow + mf * 16) = pw;                      // states row t+1
      }
    }
  }
}

// ---------------------------------------------------------------------------
// Kernel 2: states_embedded = states @ q, written transposed: out[j*M + m],
// plus fused W_out rows (jt==0 blocks only). Unchanged from round 7.
// ---------------------------------------------------------------------------
__global__ __launch_bounds__(256) void emb_kernel(
    const unsigned short* __restrict__ states,  // (M, n) bf16
    const float* __restrict__ q,                // (n, NEMB)
    const float* __restrict__ W_out,            // (2, n)
    float* __restrict__ out)                    // out[j*M + m]
{
  const int jt  = blockIdx.x;
  const int mt  = blockIdx.y;
  const int tid = threadIdx.x;
  const int w   = tid >> 6;
  const int l   = tid & 63;
  const int lg  = l >> 4;
  const int lr  = l & 15;

  __shared__ unsigned short qt[64 * 128];  // [j][k], swizzled, 16 KB
  __shared__ float wos[2 * NN];

  {
    const int j  = tid & 63;
    const int k0 = tid >> 6;
    #pragma unroll
    for (int kk = k0; kk < 128; kk += 4) {
      float v = q[kk * NEMB + jt * 64 + j];
      int k8 = kk >> 3, e = kk & 7;
      qt[j * 128 + ((k8 ^ (j & 7)) << 3) + e] = f2bf(v);
    }
  }
  if (jt == 0) wos[tid] = W_out[tid];

  s16x8 afrag[2][4];
  #pragma unroll
  for (int mf = 0; mf < 2; ++mf) {
    const int m = mt * 128 + w * 32 + mf * 16 + lr;
    const unsigned short* arow = states + m * NN;
    #pragma unroll
    for (int kc = 0; kc < 4; ++kc)
      afrag[mf][kc] = *(const s16x8*)(arow + kc * 32 + lg * 8);
  }
  __syncthreads();

  f32x4 acc[2][4] = {};
  #pragma unroll
  for (int kc = 0; kc < 4; ++kc) {
    s16x8 bfrag[4];
    #pragma unroll
    for (int jf = 0; jf < 4; ++jf) {
      const int jl = jf * 16 + lr;
      bfrag[jf] = *(const s16x8*)(qt + jl * 128 + ((((kc << 2) + lg) ^ (jl & 7)) << 3));
    }
    #pragma unroll
    for (int mf = 0; mf < 2; ++mf)
      #pragma unroll
      for (int jf = 0; jf < 4; ++jf)
        acc[mf][jf] = __builtin_amdgcn_mfma_f32_16x16x32_bf16(
            afrag[mf][kc], bfrag[jf], acc[mf][jf], 0, 0, 0);
  }

  if (jt == 0) {
    #pragma unroll
    for (int mf = 0; mf < 2; ++mf) {
      float s0 = 0.f, s1 = 0.f;
      #pragma unroll
      for (int kc = 0; kc < 4; ++kc) {
        const int kb = kc * 32 + lg * 8;
        const s16x8 af = afrag[mf][kc];
        #pragma unroll
        for (int e = 0; e < 8; ++e) {
          const float x = bf2f((unsigned short)af[e]);
          s0 = fmaf(x, wos[kb + e], s0);
          s1 = fmaf(x, wos[NN + kb + e], s1);
        }
      }
      s0 += __shfl_xor(s0, 16); s0 += __shfl_xor(s0, 32);
      s1 += __shfl_xor(s1, 16); s1 += __shfl_xor(s1, 32);
      if (lg == 0) {
        const long m = (long)mt * 128 + w * 32 + mf * 16 + lr;
        out[(long)1024 * M_ROWS + m] = s0;
        out[(long)1025 * M_ROWS + m] = s1;
      }
    }
  }

  #pragma unroll
  for (int mf = 0; mf < 2; ++mf) {
    const int m = mt * 128 + w * 32 + mf * 16 + lg * 4;
    #pragma unroll
    for (int jf = 0; jf < 4; ++jf) {
      const long j = jt * 64 + jf * 16 + lr;
      *(f32x4*)&out[j * M_ROWS + m] = acc[mf][jf];
    }
  }
}

extern "C" void kernel_launch(void* const* d_in, const int* in_sizes, int n_in,
                              void* d_out, int out_size, void* d_ws, size_t ws_size,
                              hipStream_t stream) {
  const float* u         = (const float*)d_in[0];
  const float* rec_noise = (const float*)d_in[1];
  const float* inp_noise = (const float*)d_in[2];
  const float* W_inp     = (const float*)d_in[3];
  const float* W_rec     = (const float*)d_in[4];
  const float* W_out     = (const float*)d_in[5];
  const float* q         = (const float*)d_in[6];
  float* out = (float*)d_out;
  unsigned short* states = (unsigned short*)d_ws;  // (T, B, n) bf16 = 33.6 MB

  rnn_mfma_kernel<<<dim3(BATCH / NB), dim3(64), 0, stream>>>(
      u, rec_noise, inp_noise, W_inp, W_rec, states);

  dim3 g2(NEMB / 64, M_ROWS / 128);  // (16, 1024), jt fastest for A-panel L2 reuse
  emb_kernel<<<g2, dim3(256), 0, stream>>>(states, q, W_out, out);
}

// Round 9
// 501.871 us; speedup vs baseline: 1.5493x; 1.5493x over previous
//
#include <hip/hip_runtime.h>
#include <hip/hip_bf16.h>

// Problem constants (fixed by setup_inputs)
#define T_STEPS 512
#define BATCH   256
#define NN      128                 // n
#define NEMB    1024                // N
#define M_ROWS  (T_STEPS * BATCH)   // 131072
#define NOISE_K 0.13416407864998738f  // sqrt(2/alpha * sigma^2)
#define NB      16                  // batches per block
#define CH      4                   // steps per staged noise chunk
#define NSTEP   (T_STEPS - 1)       // 511 update steps
#define NCH     ((NSTEP + CH - 1) / CH)  // 128 chunks (last runs 3 steps)

typedef short s16x8 __attribute__((ext_vector_type(8)));
typedef float f32x4 __attribute__((ext_vector_type(4)));
typedef int   s32x2 __attribute__((ext_vector_type(2)));
typedef int   s32x4 __attribute__((ext_vector_type(4)));

union FragU { s32x4 i4; s16x8 s8; };

__device__ __forceinline__ unsigned short f2bf(float f) {
  union { float f; unsigned u; } v; v.f = f;
  unsigned r = v.u + 0x7fffu + ((v.u >> 16) & 1u);  // RNE
  return (unsigned short)(r >> 16);
}
__device__ __forceinline__ float bf2f(unsigned short s) {
  union { unsigned u; float f; } v; v.u = ((unsigned)s) << 16;
  return v.f;
}
// pack two f32 -> one u32 of 2 bf16 (low = first arg), RNE
__device__ __forceinline__ unsigned pkbf(float lo, float hi) {
  __hip_bfloat162 h = __float22bfloat162_rn(float2{lo, hi});
  union { __hip_bfloat162 h; unsigned u; } c; c.h = h; return c.u;
}

// Workgroup barrier, lgkm-only, compiler-fenced on BOTH sides (r5/r6 lesson:
// s_barrier is IntrNoMem; without the trailing clobber the next step's
// ds_read hoists above it). vmcnt deliberately NOT drained.
__device__ __forceinline__ void light_barrier() {
  asm volatile("s_waitcnt lgkmcnt(0)" ::: "memory");
  __builtin_amdgcn_s_barrier();
  asm volatile("" ::: "memory");
}

// ---------------------------------------------------------------------------
// Kernel 1: leaky-RNN recurrence on the matrix pipe, 4 cooperating waves.
// r8 (1 wave/block, 8 m-tiles/wave) measured 2860 cyc/step of pure exposed
// latency (Occupancy 0.19%). Here each block (256 thr) handles one 16-batch
// group; wave w owns m-tiles {2w, 2w+1}: per step per wave only 10 MFMA
// (2 chains of 5) + ~40 VALU + 8 ds_read_b64 + 2 ds_write_b64, then ONE
// lgkm-only barrier. x exchanged via double-buffered LDS tile xld[2]
// ([f/4 row][16 batch][4 bf16], 136B rows). W_rec + W_inp (padded 6->32,
// fused as 5th K-block) resident in VGPRs as bf16 A-frags.
// rec_noise staged per-4-step chunk via swizzled-source global_load_lds
// (wave-split by batch); ONE counted vmcnt(8) per chunk boundary (the 8
// newest outstanding ops are this wave's states-stores, which never drain).
// states (bf16) written to ws in (T, B, n) layout; row m = t*B + b.
// ---------------------------------------------------------------------------
__global__ __launch_bounds__(256, 1) void rnn_mfma_kernel(
    const float* __restrict__ u,          // (6, T, B)
    const float* __restrict__ rec_noise,  // (B, T, n)
    const float* __restrict__ inp_noise,  // (B, T, 6)
    const float* __restrict__ W_inp,      // (n, 6)
    const float* __restrict__ W_rec,      // (n, n)
    unsigned short* __restrict__ states)  // (T, B, n) bf16
{
  const int b0  = blockIdx.x * NB;
  const int tid = threadIdx.x;
  const int wv  = tid >> 6;     // wave 0..3
  const int l   = tid & 63;
  const int lr  = l & 15;       // batch column | A row
  const int lg  = l >> 4;       // k-chunk / D row group

  __shared__ char           xld[2][32 * 136];      // x tiles, 2 x 4.25 KB
  __shared__ float          rns[2][NB * CH * 128]; // noise chunks, 64 KB
  __shared__ unsigned short uinl[NB * CH * 8];     // (u + K*inp) bf16, 1 KB

  // ---- W fragments (A-operand) for this wave's two m-tiles
  const int mf0 = wv * 2;
  s16x8 wA[2][5];
  #pragma unroll
  for (int mi = 0; mi < 2; ++mi) {
    const int mf = mf0 + mi;
    const float* wrow = W_rec + (size_t)(mf * 16 + lr) * NN;
    #pragma unroll
    for (int kc = 0; kc < 4; ++kc) {
      f32x4 v0 = *(const f32x4*)(wrow + kc * 32 + lg * 8);
      f32x4 v1 = *(const f32x4*)(wrow + kc * 32 + lg * 8 + 4);
      FragU f;
      f.i4 = s32x4{(int)pkbf(v0.x, v0.y), (int)pkbf(v0.z, v0.w),
                   (int)pkbf(v1.x, v1.y), (int)pkbf(v1.z, v1.w)};
      wA[mi][kc] = f.s8;
    }
    float wi[6] = {0.f, 0.f, 0.f, 0.f, 0.f, 0.f};
    if (lg == 0) {
      #pragma unroll
      for (int j = 0; j < 6; ++j) wi[j] = W_inp[(mf * 16 + lr) * 6 + j];
    }
    FragU f;
    f.i4 = s32x4{(int)pkbf(wi[0], wi[1]), (int)pkbf(wi[2], wi[3]),
                 (int)pkbf(wi[4], wi[5]), 0};
    wA[mi][4] = f.s8;
  }

  // zero xld[0] (x_0 = 0) and states row t=0 for this block's batches
  for (int i = tid; i < 1088; i += 256) ((int*)&xld[0][0])[i] = 0;
  *(s32x4*)((char*)states + (size_t)b0 * 256 + tid * 16) = s32x4{0, 0, 0, 0};

  // per-lane source-offset pattern for swizzle-on-load (s = b&7)
  int loff[8];
  #pragma unroll
  for (int s = 0; s < 8; ++s)
    loff[s] = (l >> 5) * 512 + (((l & 31) * 16) ^ (s << 4));

  // ---- prologue: stage chunk 0 (wave w stages batches wv*4..wv*4+3)
  #pragma unroll
  for (int bb = 0; bb < 4; ++bb) {
    const int b = wv * 4 + bb;
    const char* gb = (const char*)rec_noise +
                     ((size_t)(b0 + b) * T_STEPS + 0) * 512 + loff[b & 7];
    float* db = &rns[0][b * 512];
    __builtin_amdgcn_global_load_lds(
        (const __attribute__((address_space(1))) void*)gb,
        (__attribute__((address_space(3))) void*)db, 16, 0, 0);
    __builtin_amdgcn_global_load_lds(
        (const __attribute__((address_space(1))) void*)(gb + 1024),
        (__attribute__((address_space(3))) void*)(db + 256), 16, 0, 0);
  }
  float uu[6], ii[6];
  if (wv == 0) {  // lane -> (batch = lr, step = lg)
    #pragma unroll
    for (int j = 0; j < 6; ++j) {
      uu[j] = u[(size_t)j * (T_STEPS * BATCH) + (size_t)lg * BATCH + b0 + lr];
      ii[j] = inp_noise[((size_t)(b0 + lr) * T_STEPS + lg) * 6 + j];
    }
  }
  asm volatile("s_waitcnt vmcnt(0)" ::: "memory");
  if (wv == 0) {
    *(s32x2*)&uinl[(lr * 4 + lg) * 8] =
        s32x2{(int)pkbf(uu[0] + NOISE_K * ii[0], uu[1] + NOISE_K * ii[1]),
              (int)pkbf(uu[2] + NOISE_K * ii[2], uu[3] + NOISE_K * ii[3])};
    *(s32x2*)&uinl[(lr * 4 + lg) * 8 + 4] =
        s32x2{(int)pkbf(uu[4] + NOISE_K * ii[4], uu[5] + NOISE_K * ii[5]), 0};
  }
  __syncthreads();

  float xo[2][4];
  #pragma unroll
  for (int mi = 0; mi < 2; ++mi)
    #pragma unroll
    for (int r = 0; r < 4; ++r) xo[mi][r] = 0.f;

  for (int c = 0; c < NCH; ++c) {
    const int  cb   = c & 1;
    const bool more = (c + 1 < NCH);

    if (more) {  // issue next-chunk staging (lands during the 4 steps below)
      const int t0n = (c + 1) * CH;
      #pragma unroll
      for (int bb = 0; bb < 4; ++bb) {
        const int b = wv * 4 + bb;
        const char* gb = (const char*)rec_noise +
                         ((size_t)(b0 + b) * T_STEPS + t0n) * 512 + loff[b & 7];
        float* db = &rns[cb ^ 1][b * 512];
        __builtin_amdgcn_global_load_lds(
            (const __attribute__((address_space(1))) void*)gb,
            (__attribute__((address_space(3))) void*)db, 16, 0, 0);
        __builtin_amdgcn_global_load_lds(
            (const __attribute__((address_space(1))) void*)(gb + 1024),
            (__attribute__((address_space(3))) void*)(db + 256), 16, 0, 0);
      }
      if (wv == 0) {
        const int tb = t0n + lg;  // <= 511, always in-bounds
        #pragma unroll
        for (int j = 0; j < 6; ++j) {
          uu[j] = u[(size_t)j * (T_STEPS * BATCH) + (size_t)tb * BATCH + b0 + lr];
          ii[j] = inp_noise[((size_t)(b0 + lr) * T_STEPS + tb) * 6 + j];
        }
      }
    }

    #pragma unroll
    for (int ts = 0; ts < CH; ++ts) {
      const int t = c * CH + ts;
      if (t >= NSTEP) break;              // uniform: trims last chunk only
      const int cur = t & 1, nxt = cur ^ 1;

      // B fragments: x_t (bf16) from shared tile
      s16x8 xb[4];
      #pragma unroll
      for (int kc = 0; kc < 4; ++kc) {
        const char* p = xld[cur] + (kc * 8 + lg * 2) * 136 + lr * 8;
        s32x2 r1 = *(const s32x2*)p;
        s32x2 r2 = *(const s32x2*)(p + 136);
        FragU f; f.i4 = s32x4{r1.x, r1.y, r2.x, r2.y};
        xb[kc] = f.s8;
      }
      FragU uf; uf.i4 = *(const s32x4*)&uinl[(lr * 4 + ts) * 8];
      const s16x8 ub = (lg == 0) ? uf.s8 : s16x8{0, 0, 0, 0, 0, 0, 0, 0};

      unsigned short* srow =
          states + ((size_t)(t + 1) * BATCH + b0 + lr) * NN + lg * 4;

      #pragma unroll
      for (int mi = 0; mi < 2; ++mi) {
        const int mf = mf0 + mi;
        f32x4 a = f32x4{0.f, 0.f, 0.f, 0.f};
        a = __builtin_amdgcn_mfma_f32_16x16x32_bf16(wA[mi][0], xb[0], a, 0, 0, 0);
        a = __builtin_amdgcn_mfma_f32_16x16x32_bf16(wA[mi][1], xb[1], a, 0, 0, 0);
        a = __builtin_amdgcn_mfma_f32_16x16x32_bf16(wA[mi][2], xb[2], a, 0, 0, 0);
        a = __builtin_amdgcn_mfma_f32_16x16x32_bf16(wA[mi][3], xb[3], a, 0, 0, 0);
        a = __builtin_amdgcn_mfma_f32_16x16x32_bf16(wA[mi][4], ub,    a, 0, 0, 0);
        const f32x4 rn4 = *(const f32x4*)&rns[cb][lr * 512 + ts * 128 +
                               ((mf * 16 + lg * 4) ^ ((lr & 7) << 2))];
        float xn[4];
        #pragma unroll
        for (int r = 0; r < 4; ++r) {
          const float rl = fmaxf(a[r], 0.f);
          xn[r] = 0.9f * xo[mi][r] + 0.1f * (rl + NOISE_K * rn4[r]);
          xo[mi][r] = xn[r];
        }
        const s32x2 pw{(int)pkbf(xn[0], xn[1]), (int)pkbf(xn[2], xn[3])};
        *(s32x2*)(xld[nxt] + (mf * 4 + lg) * 136 + lr * 8) = pw;  // x_{t+1}
        *(s32x2*)(srow + mf * 16) = pw;                           // states
      }
      light_barrier();  // all waves' x_{t+1} visible; no vmcnt drain
    }

    if (more) {
      // Drain this wave's chunk-(c+1) loads; keep the 8 newest outstanding
      // ops (this chunk's 8 states-stores) in flight.
      asm volatile("s_waitcnt vmcnt(8)" ::: "memory");
      if (wv == 0) {
        *(s32x2*)&uinl[(lr * 4 + lg) * 8] =
            s32x2{(int)pkbf(uu[0] + NOISE_K * ii[0], uu[1] + NOISE_K * ii[1]),
                  (int)pkbf(uu[2] + NOISE_K * ii[2], uu[3] + NOISE_K * ii[3])};
        *(s32x2*)&uinl[(lr * 4 + lg) * 8 + 4] =
            s32x2{(int)pkbf(uu[4] + NOISE_K * ii[4], uu[5] + NOISE_K * ii[5]), 0};
      }
      light_barrier();  // chunk c+1 rns/uinl visible to all waves
    }
  }
}

// ---------------------------------------------------------------------------
// Kernel 2: states_embedded = states @ q, written transposed: out[j*M + m],
// plus fused W_out rows (jt==0 blocks only). Unchanged (r7, passing).
// ---------------------------------------------------------------------------
__global__ __launch_bounds__(256) void emb_kernel(
    const unsigned short* __restrict__ states,  // (M, n) bf16
    const float* __restrict__ q,                // (n, NEMB)
    const float* __restrict__ W_out,            // (2, n)
    float* __restrict__ out)                    // out[j*M + m]
{
  const int jt  = blockIdx.x;
  const int mt  = blockIdx.y;
  const int tid = threadIdx.x;
  const int w   = tid >> 6;
  const int l   = tid & 63;
  const int lg  = l >> 4;
  const int lr  = l & 15;

  __shared__ unsigned short qt[64 * 128];  // [j][k], swizzled, 16 KB
  __shared__ float wos[2 * NN];

  {
    const int j  = tid & 63;
    const int k0 = tid >> 6;
    #pragma unroll
    for (int kk = k0; kk < 128; kk += 4) {
      float v = q[kk * NEMB + jt * 64 + j];
      int k8 = kk >> 3, e = kk & 7;
      qt[j * 128 + ((k8 ^ (j & 7)) << 3) + e] = f2bf(v);
    }
  }
  if (jt == 0) wos[tid] = W_out[tid];

  s16x8 afrag[2][4];
  #pragma unroll
  for (int mf = 0; mf < 2; ++mf) {
    const int m = mt * 128 + w * 32 + mf * 16 + lr;
    const unsigned short* arow = states + m * NN;
    #pragma unroll
    for (int kc = 0; kc < 4; ++kc)
      afrag[mf][kc] = *(const s16x8*)(arow + kc * 32 + lg * 8);
  }
  __syncthreads();

  f32x4 acc[2][4] = {};
  #pragma unroll
  for (int kc = 0; kc < 4; ++kc) {
    s16x8 bfrag[4];
    #pragma unroll
    for (int jf = 0; jf < 4; ++jf) {
      const int jl = jf * 16 + lr;
      bfrag[jf] = *(const s16x8*)(qt + jl * 128 + ((((kc << 2) + lg) ^ (jl & 7)) << 3));
    }
    #pragma unroll
    for (int mf = 0; mf < 2; ++mf)
      #pragma unroll
      for (int jf = 0; jf < 4; ++jf)
        acc[mf][jf] = __builtin_amdgcn_mfma_f32_16x16x32_bf16(
            afrag[mf][kc], bfrag[jf], acc[mf][jf], 0, 0, 0);
  }

  if (jt == 0) {
    #pragma unroll
    for (int mf = 0; mf < 2; ++mf) {
      float s0 = 0.f, s1 = 0.f;
      #pragma unroll
      for (int kc = 0; kc < 4; ++kc) {
        const int kb = kc * 32 + lg * 8;
        const s16x8 af = afrag[mf][kc];
        #pragma unroll
        for (int e = 0; e < 8; ++e) {
          const float x = bf2f((unsigned short)af[e]);
          s0 = fmaf(x, wos[kb + e], s0);
          s1 = fmaf(x, wos[NN + kb + e], s1);
        }
      }
      s0 += __shfl_xor(s0, 16); s0 += __shfl_xor(s0, 32);
      s1 += __shfl_xor(s1, 16); s1 += __shfl_xor(s1, 32);
      if (lg == 0) {
        const long m = (long)mt * 128 + w * 32 + mf * 16 + lr;
        out[(long)1024 * M_ROWS + m] = s0;
        out[(long)1025 * M_ROWS + m] = s1;
      }
    }
  }

  #pragma unroll
  for (int mf = 0; mf < 2; ++mf) {
    const int m = mt * 128 + w * 32 + mf * 16 + lg * 4;
    #pragma unroll
    for (int jf = 0; jf < 4; ++jf) {
      const long j = jt * 64 + jf * 16 + lr;
      *(f32x4*)&out[j * M_ROWS + m] = acc[mf][jf];
    }
  }
}

extern "C" void kernel_launch(void* const* d_in, const int* in_sizes, int n_in,
                              void* d_out, int out_size, void* d_ws, size_t ws_size,
                              hipStream_t stream) {
  const float* u         = (const float*)d_in[0];
  const float* rec_noise = (const float*)d_in[1];
  const float* inp_noise = (const float*)d_in[2];
  const float* W_inp     = (const float*)d_in[3];
  const float* W_rec     = (const float*)d_in[4];
  const float* W_out     = (const float*)d_in[5];
  const float* q         = (const float*)d_in[6];
  float* out = (float*)d_out;
  unsigned short* states = (unsigned short*)d_ws;  // (T, B, n) bf16 = 33.6 MB

  rnn_mfma_kernel<<<dim3(BATCH / NB), dim3(256), 0, stream>>>(
      u, rec_noise, inp_noise, W_inp, W_rec, states);

  dim3 g2(NEMB / 64, M_ROWS / 128);  // (16, 1024), jt fastest for A-panel L2 reuse
  emb_kernel<<<g2, dim3(256), 0, stream>>>(states, q, W_out, out);
}